// Round 5
// baseline (71.675 us; speedup 1.0000x reference)
//
#include <hip/hip_runtime.h>

// Problem constants
#define OC_ 32
#define IC_ 16
#define H_ 32
#define W_ 32
#define B_ 8
#define TPO 144          // tables per output channel = IC*KH*KW

// LDS tile: 16 output rows + 2 halo rows, 32 cols + halo col each side.
#define ROWS_PER_WG 16
#define TR 18
#define TC 34
#define CH_STRIDE (TR * TC)          // 612 dwords per channel plane
#define TILE_F (IC_ * CH_STRIDE)     // 9792 floats = 39168 B

// 16-B packed record -> one ds_read_b128 (broadcast) per table.
// offs = byte_off0 | (byte_off1 << 16); byte offsets (off*4), max 39164 < 65536.
// out_t = aa(folded into per-block bias) + bb*x0 + cc*x1 + dd*x0*x1
struct alignas(16) Rec4 { unsigned offs; float bb, cc, dd; };

// Each thread owns two VERTICALLY ADJACENT positions (rows 2*rl, 2*rl+1).
// Both gathers for a table then come from one base pointer at dword offsets
// 0 and TC(=34) -> the load-store optimizer's standard ds_read2_b32 pattern
// (R4's 320-dword st64 variant never formed; 34 <= 255 is the reliable path).
__global__ __launch_bounds__(256)
void conv_kernel(const float* __restrict__ input,
                 const float* __restrict__ w_luts,
                 const int*   __restrict__ mask_c,
                 const int*   __restrict__ mask_kh,
                 const int*   __restrict__ mask_kw,
                 float*       __restrict__ out) {
    __shared__ float tile[TILE_F];
    __shared__ Rec4  srec[TPO];
    __shared__ float sAA[TPO];
    __shared__ float sP[8];

    const int oh0 = blockIdx.x * ROWS_PER_WG;   // grid.x = 2
    const int oc  = blockIdx.y;
    const int b   = blockIdx.z;
    const int tid = threadIdx.x;

    // --- build this oc's 144 packed records (threads 0..143)
    if (tid < TPO) {
        int t = oc * TPO + tid;
        const float4 w = *reinterpret_cast<const float4*>(w_luts + 4 * t);
        int m0 = 2 * t, m1 = m0 + 1;
        unsigned off0 = (unsigned)(mask_c[m0] * CH_STRIDE + mask_kh[m0] * TC + mask_kw[m0]) * 4u;
        unsigned off1 = (unsigned)(mask_c[m1] * CH_STRIDE + mask_kh[m1] * TC + mask_kw[m1]) * 4u;
        Rec4 r;
        r.offs = off0 | (off1 << 16);
        r.bb = 0.25f * (-w.x + w.y - w.z + w.w);
        r.cc = 0.25f * (-w.x - w.y + w.z + w.w);
        r.dd = 0.25f * ( w.x - w.y - w.z + w.w);
        srec[tid] = r;
        sAA[tid]  = 0.25f * (w.x + w.y + w.z + w.w);
    }

    // --- stage input tile: 16 ch x 18 rows x 32 interior cols, float4 loads
    const float* inb = input + b * (IC_ * H_ * W_);
    for (int u = tid; u < IC_ * TR * 8; u += 256) {   // 2304 float4 units
        int ch  = u / (TR * 8);
        int rem = u - ch * (TR * 8);
        int r   = rem >> 3;
        int c4  = (rem & 7) * 4;
        int grow = oh0 + r - 1;
        float4 v = make_float4(0.f, 0.f, 0.f, 0.f);
        if ((unsigned)grow < (unsigned)H_)
            v = *reinterpret_cast<const float4*>(inb + (ch * H_ + grow) * W_ + c4);
        float* dst = &tile[ch * CH_STRIDE + r * TC + 1 + c4];
        dst[0] = v.x; dst[1] = v.y; dst[2] = v.z; dst[3] = v.w;
    }
    // zero halo columns 0 and 33
    for (int i = tid; i < IC_ * TR * 2; i += 256) {
        int ch  = i / (TR * 2);
        int rem = i - ch * (TR * 2);
        int r   = rem >> 1;
        int cc2 = (rem & 1) ? (TC - 1) : 0;
        tile[ch * CH_STRIDE + r * TC + cc2] = 0.f;
    }
    __syncthreads();

    // --- fold constant terms into one per-block bias
    if (tid < 8) {
        float s = 0.f;
        #pragma unroll
        for (int i = 0; i < 18; ++i) s += sAA[tid * 18 + i];
        sP[tid] = s;
    }
    __syncthreads();
    const float bias = ((sP[0] + sP[1]) + (sP[2] + sP[3]))
                     + ((sP[4] + sP[5]) + (sP[6] + sP[7]));

    // --- hot loop: 144 tables x 2 adjacent-row positions per thread.
    // Per table: 1x ds_read_b128 (rec, broadcast) + 2x ds_read2_b32 (gathers)
    // + 10 VALU (2 unpack, 2 addr add, 6 FMA).
    const int rl = tid >> 5;                    // 0..7 -> rows 2rl, 2rl+1
    const int ow = tid & 31;
    const char* tb = (const char*)tile + ((2 * rl) * TC + ow) * 4;
    const int4* sq = reinterpret_cast<const int4*>(srec);

    float accA = 0.f, accB = 0.f;
    #pragma unroll 8
    for (int t = 0; t < TPO; ++t) {
        const int4 q = sq[t];
        const unsigned offs = (unsigned)q.x;
        const float* g0 = reinterpret_cast<const float*>(tb + (offs & 0xffffu));
        const float* g1 = reinterpret_cast<const float*>(tb + (offs >> 16));
        const float x0a = g0[0];
        const float x0b = g0[TC];      // ds_read2_b32 offset0:0 offset1:34
        const float x1a = g1[0];
        const float x1b = g1[TC];
        const float bb = __int_as_float(q.y);
        const float cc = __int_as_float(q.z);
        const float dd = __int_as_float(q.w);
        accA = fmaf(bb, x0a, accA);
        accA = fmaf(x1a, fmaf(dd, x0a, cc), accA);
        accB = fmaf(bb, x0b, accB);
        accB = fmaf(x1b, fmaf(dd, x0b, cc), accB);
    }

    const int ohA = oh0 + 2 * rl;
    out[((b * OC_ + oc) * H_ + ohA    ) * W_ + ow] = accA + bias;
    out[((b * OC_ + oc) * H_ + ohA + 1) * W_ + ow] = accB + bias;
}

extern "C" void kernel_launch(void* const* d_in, const int* in_sizes, int n_in,
                              void* d_out, int out_size, void* d_ws, size_t ws_size,
                              hipStream_t stream) {
    const float* input   = (const float*)d_in[0];
    const float* w_luts  = (const float*)d_in[1];
    const int*   mask_c  = (const int*)d_in[2];
    const int*   mask_kh = (const int*)d_in[3];
    const int*   mask_kw = (const int*)d_in[4];
    float* out = (float*)d_out;

    conv_kernel<<<dim3(H_ / ROWS_PER_WG, OC_, B_), dim3(256), 0, stream>>>(
        input, w_luts, mask_c, mask_kh, mask_kw, out);
}

// Round 6
// 70.241 us; speedup vs baseline: 1.0204x; 1.0204x over previous
//
#include <hip/hip_runtime.h>

// Problem constants
#define OC_ 32
#define IC_ 16
#define H_ 32
#define W_ 32
#define B_ 8
#define TPO 144          // tables per output channel = IC*KH*KW

// LDS tile: 16 output rows + 2 halo rows, 32 cols + halo col each side.
#define ROWS_PER_WG 16
#define TR 18
#define TC 34
#define CH_STRIDE (TR * TC)          // 612 dwords per channel plane
#define TILE_F (IC_ * CH_STRIDE)     // 9792 floats = 39168 B

#define NQ 4                         // table-quarters (waves split the table loop)
#define TQ (TPO / NQ)                // 36 tables per quarter
#define NTHR 1024                    // 256 positions x 4 quarters

// 16-B packed record -> one ds_read_b128 (broadcast) per table.
// offs = byte_off0 | (byte_off1 << 16); max 37000 < 65536.
// out_t = aa(folded into per-block bias) + bb*x0 + cc*x1 + dd*x0*x1
struct alignas(16) Rec4 { unsigned offs; float bb, cc, dd; };

// R3-R5 lesson: three different hot-loop DS structures all landed at conv~30us
// because 512 blocks x 256 thr = 2 waves/SIMD cannot hide ~120cyc LDS latency
// (R2 at 4 waves/SIMD saturated its DS floor; R3-5 at 2 waves sat at ~45%).
// Fix: 1024-thread blocks, 4 waves share each position set and split the 144
// tables 4-way -> 32 waves/CU, same total DS work, 8KB LDS reduction to merge.
__global__ __launch_bounds__(NTHR, 8)
void conv_kernel(const float* __restrict__ input,
                 const float* __restrict__ w_luts,
                 const int*   __restrict__ mask_c,
                 const int*   __restrict__ mask_kh,
                 const int*   __restrict__ mask_kw,
                 float*       __restrict__ out) {
    __shared__ float tile[TILE_F];
    __shared__ Rec4  srec[TPO];
    __shared__ float sAA[TPO];
    __shared__ float sP[8];
    __shared__ float redA[NTHR];
    __shared__ float redB[NTHR];

    const int oh0 = blockIdx.x * ROWS_PER_WG;   // grid.x = 2
    const int oc  = blockIdx.y;
    const int b   = blockIdx.z;
    const int tid = threadIdx.x;

    // --- build this oc's 144 packed records (threads 0..143)
    if (tid < TPO) {
        int t = oc * TPO + tid;
        const float4 w = *reinterpret_cast<const float4*>(w_luts + 4 * t);
        int m0 = 2 * t, m1 = m0 + 1;
        unsigned off0 = (unsigned)(mask_c[m0] * CH_STRIDE + mask_kh[m0] * TC + mask_kw[m0]) * 4u;
        unsigned off1 = (unsigned)(mask_c[m1] * CH_STRIDE + mask_kh[m1] * TC + mask_kw[m1]) * 4u;
        Rec4 r;
        r.offs = off0 | (off1 << 16);
        r.bb = 0.25f * (-w.x + w.y - w.z + w.w);
        r.cc = 0.25f * (-w.x - w.y + w.z + w.w);
        r.dd = 0.25f * ( w.x - w.y - w.z + w.w);
        srec[tid] = r;
        sAA[tid]  = 0.25f * (w.x + w.y + w.z + w.w);
    }

    // --- stage input tile: 16 ch x 18 rows x 32 interior cols, float4 loads
    const float* inb = input + b * (IC_ * H_ * W_);
    for (int u = tid; u < IC_ * TR * 8; u += NTHR) {   // 2304 float4 units
        int ch  = u / (TR * 8);
        int rem = u - ch * (TR * 8);
        int r   = rem >> 3;
        int c4  = (rem & 7) * 4;
        int grow = oh0 + r - 1;
        float4 v = make_float4(0.f, 0.f, 0.f, 0.f);
        if ((unsigned)grow < (unsigned)H_)
            v = *reinterpret_cast<const float4*>(inb + (ch * H_ + grow) * W_ + c4);
        float* dst = &tile[ch * CH_STRIDE + r * TC + 1 + c4];
        dst[0] = v.x; dst[1] = v.y; dst[2] = v.z; dst[3] = v.w;
    }
    // zero halo columns 0 and 33
    for (int i = tid; i < IC_ * TR * 2; i += NTHR) {
        int ch  = i / (TR * 2);
        int rem = i - ch * (TR * 2);
        int r   = rem >> 1;
        int cc2 = (rem & 1) ? (TC - 1) : 0;
        tile[ch * CH_STRIDE + r * TC + cc2] = 0.f;
    }
    __syncthreads();

    // constant-term partial fold (read after the post-loop barrier)
    if (tid < 8) {
        float s = 0.f;
        #pragma unroll
        for (int i = 0; i < 18; ++i) s += sAA[tid * 18 + i];
        sP[tid] = s;
    }

    // --- hot loop: 36 tables x 2 adjacent-row positions per thread.
    // Per table: 1x ds_read_b128 (rec, broadcast) + 2x ds_read2_b32 (gathers).
    const int pos = tid & 255;
    const int qt  = tid >> 8;                   // table quarter 0..3
    const int rl  = pos >> 5;                   // rows 2rl, 2rl+1
    const int ow  = pos & 31;
    const char* tb = (const char*)tile + ((2 * rl) * TC + ow) * 4;
    const int4* sq = reinterpret_cast<const int4*>(srec);

    float accA = 0.f, accB = 0.f;
    const int t0 = qt * TQ;
    #pragma unroll 6
    for (int t = t0; t < t0 + TQ; ++t) {
        const int4 q = sq[t];
        const unsigned offs = (unsigned)q.x;
        const float* g0 = reinterpret_cast<const float*>(tb + (offs & 0xffffu));
        const float* g1 = reinterpret_cast<const float*>(tb + (offs >> 16));
        const float x0a = g0[0];
        const float x0b = g0[TC];      // ds_read2_b32 offset0:0 offset1:34
        const float x1a = g1[0];
        const float x1b = g1[TC];
        const float bb = __int_as_float(q.y);
        const float cc = __int_as_float(q.z);
        const float dd = __int_as_float(q.w);
        accA = fmaf(bb, x0a, accA);
        accA = fmaf(x1a, fmaf(dd, x0a, cc), accA);
        accB = fmaf(bb, x0b, accB);
        accB = fmaf(x1b, fmaf(dd, x0b, cc), accB);
    }
    redA[tid] = accA;
    redB[tid] = accB;
    __syncthreads();

    // --- merge the 4 table-quarters and store
    if (tid < 256) {
        const float bias = ((sP[0] + sP[1]) + (sP[2] + sP[3]))
                         + ((sP[4] + sP[5]) + (sP[6] + sP[7]));
        float a = (redA[tid] + redA[tid + 256]) + (redA[tid + 512] + redA[tid + 768]);
        float bsum = (redB[tid] + redB[tid + 256]) + (redB[tid + 512] + redB[tid + 768]);
        const int ohA = oh0 + 2 * rl;
        out[((b * OC_ + oc) * H_ + ohA    ) * W_ + ow] = a + bias;
        out[((b * OC_ + oc) * H_ + ohA + 1) * W_ + ow] = bsum + bias;
    }
}

extern "C" void kernel_launch(void* const* d_in, const int* in_sizes, int n_in,
                              void* d_out, int out_size, void* d_ws, size_t ws_size,
                              hipStream_t stream) {
    const float* input   = (const float*)d_in[0];
    const float* w_luts  = (const float*)d_in[1];
    const int*   mask_c  = (const int*)d_in[2];
    const int*   mask_kh = (const int*)d_in[3];
    const int*   mask_kw = (const int*)d_in[4];
    float* out = (float*)d_out;

    conv_kernel<<<dim3(H_ / ROWS_PER_WG, OC_, B_), dim3(NTHR), 0, stream>>>(
        input, w_luts, mask_c, mask_kh, mask_kw, out);
}

// Round 7
// 69.752 us; speedup vs baseline: 1.0276x; 1.0070x over previous
//
#include <hip/hip_runtime.h>

// Problem constants
#define OC_ 32
#define IC_ 16
#define H_ 32
#define W_ 32
#define B_ 8
#define TPO 144          // tables per output channel = IC*KH*KW

// Full-image LDS tile: 32 rows + 2 halo, 32 cols + 2 halo, zero-padded.
#define TRF 34
#define TC 34
#define CH_STRIDE (TRF * TC)         // 1156 dwords per channel plane
#define TILE_F (IC_ * CH_STRIDE)     // 18496 dwords = 73984 B

#define NQ 4                         // table groups (waves split the table loop)
#define TQ (TPO / NQ)                // 36 tables per group
#define NTHR 1024                    // 256 position-threads x 4 groups

// 16-B packed record -> one ds_read_b128 (broadcast) per table.
// offs = dword_off0 | (dword_off1 << 16); max 17410 < 65536.
// out_t = aa(folded into per-block bias) + bb*x0 + cc*x1 + dd*x0*x1
struct alignas(16) Rec4 { unsigned offs; float bb, cc, dd; };

// R3-R6 lesson: conv time tracks the per-wave-table SERIAL cost (DS+VALU sum,
// ~58 cyc at P=2) regardless of occupancy (8 vs 32 waves/CU identical). The
// only lever that moved it was amortization per position. Here P=4 adjacent
// rows/thread: rec amortized 4x, gathers as 4x ds_read2_b32 (offsets 0/34 and
// 68/102 off one base, conflict-free), ~19.5 cyc/pos vs ~29.
__global__ __launch_bounds__(NTHR, 1)
void conv_kernel(const float* __restrict__ input,
                 const float* __restrict__ w_luts,
                 const int*   __restrict__ mask_c,
                 const int*   __restrict__ mask_kh,
                 const int*   __restrict__ mask_kw,
                 float*       __restrict__ out) {
    __shared__ float tile[TILE_F];
    __shared__ Rec4  srec[TPO];
    __shared__ float sAA[TPO];
    __shared__ float sP[8];
    __shared__ float redA[NTHR];
    __shared__ float redB[NTHR];
    __shared__ float redC[NTHR];
    __shared__ float redD[NTHR];

    const int oc  = blockIdx.x;
    const int b   = blockIdx.y;
    const int tid = threadIdx.x;

    // --- build this oc's 144 packed records (threads 0..143)
    if (tid < TPO) {
        int t = oc * TPO + tid;
        const float4 w = *reinterpret_cast<const float4*>(w_luts + 4 * t);
        int m0 = 2 * t, m1 = m0 + 1;
        unsigned off0 = (unsigned)(mask_c[m0] * CH_STRIDE + mask_kh[m0] * TC + mask_kw[m0]);
        unsigned off1 = (unsigned)(mask_c[m1] * CH_STRIDE + mask_kh[m1] * TC + mask_kw[m1]);
        Rec4 r;
        r.offs = off0 | (off1 << 16);
        r.bb = 0.25f * (-w.x + w.y - w.z + w.w);
        r.cc = 0.25f * (-w.x - w.y + w.z + w.w);
        r.dd = 0.25f * ( w.x - w.y - w.z + w.w);
        srec[tid] = r;
        sAA[tid]  = 0.25f * (w.x + w.y + w.z + w.w);
    }

    // --- stage the full image for batch b: 16 ch x 32 x 32 interior, float4
    const float* inb = input + b * (IC_ * H_ * W_);
    for (int u = tid; u < IC_ * H_ * 8; u += NTHR) {   // 4096 float4 units, 4 iters
        int ch  = u >> 8;
        int rem = u & 255;
        int r   = rem >> 3;
        int c4  = (rem & 7) * 4;
        const float4 v = *reinterpret_cast<const float4*>(inb + (ch * H_ + r) * W_ + c4);
        float* dst = &tile[ch * CH_STRIDE + (r + 1) * TC + 1 + c4];
        dst[0] = v.x; dst[1] = v.y; dst[2] = v.z; dst[3] = v.w;
    }
    // zero halo rows 0 and 33
    for (int i = tid; i < IC_ * 2 * TC; i += NTHR) {   // 1088
        int ch  = i / (2 * TC);
        int rem = i - ch * (2 * TC);
        int row = (rem >= TC) ? (TRF - 1) : 0;
        int col = (rem >= TC) ? (rem - TC) : rem;
        tile[ch * CH_STRIDE + row * TC + col] = 0.f;
    }
    // zero halo cols 0 and 33
    for (int i = tid; i < IC_ * TRF * 2; i += NTHR) {  // 1088
        int ch  = i / (TRF * 2);
        int rem = i - ch * (TRF * 2);
        int r   = rem >> 1;
        int col = (rem & 1) ? (TC - 1) : 0;
        tile[ch * CH_STRIDE + r * TC + col] = 0.f;
    }
    __syncthreads();

    // constant-term partial fold (read after the post-loop barrier)
    if (tid < 8) {
        float s = 0.f;
        #pragma unroll
        for (int i = 0; i < 18; ++i) s += sAA[tid * 18 + i];
        sP[tid] = s;
    }

    // --- hot loop: 36 tables x 4 adjacent-row positions per thread.
    const int g  = tid >> 8;                    // table group 0..3
    const int p  = tid & 255;
    const int rl = p >> 5;                      // rows 4rl .. 4rl+3
    const int ow = p & 31;
    const float* tb = &tile[(4 * rl) * TC + ow];
    const int4* sq = reinterpret_cast<const int4*>(srec);

    float a0 = 0.f, a1 = 0.f, a2 = 0.f, a3 = 0.f;
    const int t0 = g * TQ;
    #pragma unroll 6
    for (int t = t0; t < t0 + TQ; ++t) {
        const int4 q = sq[t];                   // ds_read_b128 broadcast
        const unsigned offs = (unsigned)q.x;
        const float* g0 = tb + (offs & 0xffffu);
        const float* g1 = tb + (offs >> 16);
        // rows 4rl..4rl+3: pairs (0,34) and (68,102) -> 2x ds_read2_b32 each
        const float x00 = g0[0];
        const float x01 = g0[TC];
        const float x02 = g0[2 * TC];
        const float x03 = g0[3 * TC];
        const float x10 = g1[0];
        const float x11 = g1[TC];
        const float x12 = g1[2 * TC];
        const float x13 = g1[3 * TC];
        const float bb = __int_as_float(q.y);
        const float cc = __int_as_float(q.z);
        const float dd = __int_as_float(q.w);
        a0 = fmaf(bb, x00, a0);  a0 = fmaf(x10, fmaf(dd, x00, cc), a0);
        a1 = fmaf(bb, x01, a1);  a1 = fmaf(x11, fmaf(dd, x01, cc), a1);
        a2 = fmaf(bb, x02, a2);  a2 = fmaf(x12, fmaf(dd, x02, cc), a2);
        a3 = fmaf(bb, x03, a3);  a3 = fmaf(x13, fmaf(dd, x03, cc), a3);
    }
    redA[tid] = a0; redB[tid] = a1; redC[tid] = a2; redD[tid] = a3;
    __syncthreads();

    // --- merge the 4 table groups and store 4 rows per thread
    if (tid < 256) {
        const float bias = ((sP[0] + sP[1]) + (sP[2] + sP[3]))
                         + ((sP[4] + sP[5]) + (sP[6] + sP[7]));
        float s0 = (redA[tid] + redA[tid + 256]) + (redA[tid + 512] + redA[tid + 768]);
        float s1 = (redB[tid] + redB[tid + 256]) + (redB[tid + 512] + redB[tid + 768]);
        float s2 = (redC[tid] + redC[tid + 256]) + (redC[tid + 512] + redC[tid + 768]);
        float s3 = (redD[tid] + redD[tid + 256]) + (redD[tid + 512] + redD[tid + 768]);
        const int y0 = 4 * rl;
        float* ob = out + ((b * OC_ + oc) * H_ + y0) * W_ + ow;
        ob[0 * W_] = s0 + bias;
        ob[1 * W_] = s1 + bias;
        ob[2 * W_] = s2 + bias;
        ob[3 * W_] = s3 + bias;
    }
}

extern "C" void kernel_launch(void* const* d_in, const int* in_sizes, int n_in,
                              void* d_out, int out_size, void* d_ws, size_t ws_size,
                              hipStream_t stream) {
    const float* input   = (const float*)d_in[0];
    const float* w_luts  = (const float*)d_in[1];
    const int*   mask_c  = (const int*)d_in[2];
    const int*   mask_kh = (const int*)d_in[3];
    const int*   mask_kw = (const int*)d_in[4];
    float* out = (float*)d_out;

    conv_kernel<<<dim3(OC_, B_), dim3(NTHR), 0, stream>>>(
        input, w_luts, mask_c, mask_kh, mask_kw, out);
}

// Round 8
// 69.618 us; speedup vs baseline: 1.0296x; 1.0019x over previous
//
#include <hip/hip_runtime.h>

// Problem constants
#define OC_ 32
#define IC_ 16
#define H_ 32
#define W_ 32
#define B_ 8
#define TPO 144          // tables per output channel = IC*KH*KW

// Full-image LDS tile: 32 rows + 2 halo, 32 cols + 2 halo, zero-padded.
#define TRF 34
#define TC 34
#define CH_STRIDE (TRF * TC)         // 1156 dwords per channel plane
#define TILE_F (IC_ * CH_STRIDE)     // 18496 dwords = 73984 B

#define NG 8                         // table groups (waves split the table loop)
#define TG (TPO / NG)                // 18 tables per group
#define NTHR 1024                    // 128 position-threads x 8 groups
#define NPOS 128                     // 32 cols x 4 row-groups (8 rows each)

// 16-B packed record -> one ds_read_b128 (broadcast) per table.
// offs = dword_off0 | (dword_off1 << 16); max 17410 < 65536.
// out_t = aa(folded into per-block bias) + bb*x0 + cc*x1 + dd*x0*x1
struct alignas(16) Rec4 { unsigned offs; float bb, cc, dd; };

// R3-R7 post-mortems: five hot-loop structures all ~flat => conv is already
// ~10-13us and the visible ~70us is dominated by the harness's 268MB ws-poison
// fill (41us) + replay overhead. This round: P=8 rows/thread (ds_read2 offsets
// 0/34..204/238, all <=255) halves wave-table count again -> conv ~7-9us.
// If this lands <1.5us of R7, remaining time is harness-structural.
__global__ __launch_bounds__(NTHR, 1)
void conv_kernel(const float* __restrict__ input,
                 const float* __restrict__ w_luts,
                 const int*   __restrict__ mask_c,
                 const int*   __restrict__ mask_kh,
                 const int*   __restrict__ mask_kw,
                 float*       __restrict__ out) {
    __shared__ float tile[TILE_F];
    __shared__ Rec4  srec[TPO];
    __shared__ float sAA[TPO];
    __shared__ float sP[8];
    __shared__ float red[NG * NTHR / 8 * 8];   // 8 accs x 1024 threads = 32 KB

    const int oc  = blockIdx.x;
    const int b   = blockIdx.y;
    const int tid = threadIdx.x;

    // --- build this oc's 144 packed records (threads 0..143)
    if (tid < TPO) {
        int t = oc * TPO + tid;
        const float4 w = *reinterpret_cast<const float4*>(w_luts + 4 * t);
        int m0 = 2 * t, m1 = m0 + 1;
        unsigned off0 = (unsigned)(mask_c[m0] * CH_STRIDE + mask_kh[m0] * TC + mask_kw[m0]);
        unsigned off1 = (unsigned)(mask_c[m1] * CH_STRIDE + mask_kh[m1] * TC + mask_kw[m1]);
        Rec4 r;
        r.offs = off0 | (off1 << 16);
        r.bb = 0.25f * (-w.x + w.y - w.z + w.w);
        r.cc = 0.25f * (-w.x - w.y + w.z + w.w);
        r.dd = 0.25f * ( w.x - w.y - w.z + w.w);
        srec[tid] = r;
        sAA[tid]  = 0.25f * (w.x + w.y + w.z + w.w);
    }

    // --- stage the full image for batch b: 16 ch x 32 x 32 interior, float4
    const float* inb = input + b * (IC_ * H_ * W_);
    for (int u = tid; u < IC_ * H_ * 8; u += NTHR) {   // 4096 float4 units
        int ch  = u >> 8;
        int rem = u & 255;
        int r   = rem >> 3;
        int c4  = (rem & 7) * 4;
        const float4 v = *reinterpret_cast<const float4*>(inb + (ch * H_ + r) * W_ + c4);
        float* dst = &tile[ch * CH_STRIDE + (r + 1) * TC + 1 + c4];
        dst[0] = v.x; dst[1] = v.y; dst[2] = v.z; dst[3] = v.w;
    }
    // zero halo rows 0 and 33
    for (int i = tid; i < IC_ * 2 * TC; i += NTHR) {
        int ch  = i / (2 * TC);
        int rem = i - ch * (2 * TC);
        int row = (rem >= TC) ? (TRF - 1) : 0;
        int col = (rem >= TC) ? (rem - TC) : rem;
        tile[ch * CH_STRIDE + row * TC + col] = 0.f;
    }
    // zero halo cols 0 and 33
    for (int i = tid; i < IC_ * TRF * 2; i += NTHR) {
        int ch  = i / (TRF * 2);
        int rem = i - ch * (TRF * 2);
        int r   = rem >> 1;
        int col = (rem & 1) ? (TC - 1) : 0;
        tile[ch * CH_STRIDE + r * TC + col] = 0.f;
    }
    __syncthreads();

    // constant-term partial fold (read after the post-loop barrier)
    if (tid < 8) {
        float s = 0.f;
        #pragma unroll
        for (int i = 0; i < 18; ++i) s += sAA[tid * 18 + i];
        sP[tid] = s;
    }

    // --- hot loop: 18 tables x 8 adjacent-row positions per thread.
    // Per table: 1x ds_read_b128 (rec) + 8x ds_read2_b32-paired gathers.
    const int g  = tid >> 7;                    // table group 0..7
    const int p  = tid & (NPOS - 1);
    const int rl = p >> 5;                      // rows 8rl .. 8rl+7
    const int ow = p & 31;
    const float* tb = &tile[(8 * rl) * TC + ow];
    const int4* sq = reinterpret_cast<const int4*>(srec);

    float acc[8];
    #pragma unroll
    for (int i = 0; i < 8; ++i) acc[i] = 0.f;

    const int t0 = g * TG;
    #pragma unroll 6
    for (int t = t0; t < t0 + TG; ++t) {
        const int4 q = sq[t];                   // ds_read_b128 broadcast
        const unsigned offs = (unsigned)q.x;
        const float* g0 = tb + (offs & 0xffffu);
        const float* g1 = tb + (offs >> 16);
        float x0[8], x1[8];
        #pragma unroll
        for (int i = 0; i < 8; ++i) { x0[i] = g0[i * TC]; x1[i] = g1[i * TC]; }
        const float bb = __int_as_float(q.y);
        const float cc = __int_as_float(q.z);
        const float dd = __int_as_float(q.w);
        #pragma unroll
        for (int i = 0; i < 8; ++i) {
            acc[i] = fmaf(bb, x0[i], acc[i]);
            acc[i] = fmaf(x1[i], fmaf(dd, x0[i], cc), acc[i]);
        }
    }
    #pragma unroll
    for (int i = 0; i < 8; ++i) red[i * NTHR + tid] = acc[i];
    __syncthreads();

    // --- merge the 8 table groups; 256 threads each handle 4 accs of one pos
    if (tid < 2 * NPOS) {
        const float bias = ((sP[0] + sP[1]) + (sP[2] + sP[3]))
                         + ((sP[4] + sP[5]) + (sP[6] + sP[7]));
        const int pp   = tid & (NPOS - 1);
        const int half = tid >> 7;              // accs 4*half .. 4*half+3
        const int prl  = pp >> 5;
        const int pow_ = pp & 31;
        float* ob = out + ((b * OC_ + oc) * H_ + 8 * prl + 4 * half) * W_ + pow_;
        #pragma unroll
        for (int i = 0; i < 4; ++i) {
            const float* rr = &red[(4 * half + i) * NTHR + pp];
            float s = ((rr[0] + rr[NPOS]) + (rr[2 * NPOS] + rr[3 * NPOS]))
                    + ((rr[4 * NPOS] + rr[5 * NPOS]) + (rr[6 * NPOS] + rr[7 * NPOS]));
            ob[i * W_] = s + bias;
        }
    }
}

extern "C" void kernel_launch(void* const* d_in, const int* in_sizes, int n_in,
                              void* d_out, int out_size, void* d_ws, size_t ws_size,
                              hipStream_t stream) {
    const float* input   = (const float*)d_in[0];
    const float* w_luts  = (const float*)d_in[1];
    const int*   mask_c  = (const int*)d_in[2];
    const int*   mask_kh = (const int*)d_in[3];
    const int*   mask_kw = (const int*)d_in[4];
    float* out = (float*)d_out;

    conv_kernel<<<dim3(OC_, B_), dim3(NTHR), 0, stream>>>(
        input, w_luts, mask_c, mask_kh, mask_kw, out);
}